// Round 10
// baseline (15.135 us; speedup 1.0000x reference)
//
#include <hip/hip_runtime.h>
#include <hip/hip_bf16.h>

// SlotModel: B=2048, L=512, H=64, VOCAB=64, k=6 slots.
// h[b,l] depends only on token id -> 64-entry tables + per-batch top-6 scan.
// Structure (measured rounds 3..9): 2 plain dispatches, non-redundant
// producer; all single-dispatch variants are worse (spin 155us, grid.sync
// 55us, redundant producer capped at parity by VALU arithmetic).
// This round: k_tables critical path cut ~3x via 256-thr blocks with k-split
// partial sums (serial FMA 320 -> ~96). k_attn identical to round 9 (13.9us).

#define LSEQ 512
#define BODY 509       // L-3 positions eligible for slots
#define KSLOTS 6
#define INF_KEY 0x7FFFFFFF

__device__ __forceinline__ float wsum(float x) {
#pragma unroll
  for (int off = 32; off >= 1; off >>= 1) x += __shfl_xor(x, off, 64);
  return x;
}

// ---- DPP full-wave reductions (rocPRIM wave64 pattern; verified round 9) ----
__device__ __forceinline__ int dpp_wave_min_i32(int x) {
  int t;
  t = __builtin_amdgcn_update_dpp(INF_KEY, x, 0x111, 0xf, 0xf, false); x = min(x, t);
  t = __builtin_amdgcn_update_dpp(INF_KEY, x, 0x112, 0xf, 0xf, false); x = min(x, t);
  t = __builtin_amdgcn_update_dpp(INF_KEY, x, 0x114, 0xf, 0xf, false); x = min(x, t);
  t = __builtin_amdgcn_update_dpp(INF_KEY, x, 0x118, 0xf, 0xf, false); x = min(x, t);
  t = __builtin_amdgcn_update_dpp(INF_KEY, x, 0x142, 0xf, 0xf, false); x = min(x, t);
  t = __builtin_amdgcn_update_dpp(INF_KEY, x, 0x143, 0xf, 0xf, false); x = min(x, t);
  return __builtin_amdgcn_readlane(x, 63);
}
__device__ __forceinline__ float dpp_wave_sum_f32(float x) {
  int t;
  t = __builtin_amdgcn_update_dpp(0, __float_as_int(x), 0x111, 0xf, 0xf, false); x += __int_as_float(t);
  t = __builtin_amdgcn_update_dpp(0, __float_as_int(x), 0x112, 0xf, 0xf, false); x += __int_as_float(t);
  t = __builtin_amdgcn_update_dpp(0, __float_as_int(x), 0x114, 0xf, 0xf, false); x += __int_as_float(t);
  t = __builtin_amdgcn_update_dpp(0, __float_as_int(x), 0x118, 0xf, 0xf, false); x += __int_as_float(t);
  t = __builtin_amdgcn_update_dpp(0, __float_as_int(x), 0x142, 0xf, 0xf, false); x += __int_as_float(t);
  t = __builtin_amdgcn_update_dpp(0, __float_as_int(x), 0x143, 0xf, 0xf, false); x += __int_as_float(t);
  return __int_as_float(__builtin_amdgcn_readlane(__float_as_int(x), 63));
}
__device__ __forceinline__ float readlane_f(float x, int u) {
  return __int_as_float(__builtin_amdgcn_readlane(__float_as_int(x), u));
}

// Dtype probe (verified rounds 2-9): first 256 ushorts of embed.
__device__ __forceinline__ bool probe_bf16(const void* embed) {
  const ushort* e = (const ushort*)embed;
  const int lane = threadIdx.x & 63;
  bool bad = false;
#pragma unroll
  for (int i = 0; i < 4; ++i) {
    const int exp = (e[lane * 4 + i] >> 7) & 0xFF;
    if (exp >= 127) bad = true;
  }
  return !__any(bad);
}

template <bool BF>
__device__ __forceinline__ float ldel(const void* p, int i) {
  if (BF) return __bfloat162float(((const __hip_bfloat16*)p)[i]);
  return ((const float*)p)[i];
}

// ---- K1: 64 blocks x 256 threads, one token each. k-split partial sums. ----
template <bool BF>
__device__ __forceinline__ void k1_body(
    const void* embed, const void* W1, const void* b1, const void* W2,
    const void* b2, const void* gamma, const void* beta, const void* Wq,
    const void* bq, const void* Wo, const void* bo, float* h_table,
    float* norm_table, float* q_table, float* out_table) {
  const int v = blockIdx.x, tid = threadIdx.x;
  __shared__ float e_s[64];
  __shared__ float part1[2][128];   // layer-1 partials (2-way k-split)
  __shared__ float h1_s[128];
  __shared__ float part2[4][64];    // layer-2 partials (4-way j-split)
  __shared__ float h_s[64];
  __shared__ float partq[2][2][64]; // q/out partials (2-way i-split)

  if (tid < 64) e_s[tid] = ldel<BF>(embed, v * 64 + tid);
  __syncthreads();

  // layer 1: out col c = tid&127, k-half = tid>>7 (32 iters each)
  {
    const int c = tid & 127, half = tid >> 7;
    const int k0 = half * 32;
    float acc = half ? 0.f : ldel<BF>(b1, c);
#pragma unroll
    for (int k = 0; k < 32; ++k)
      acc += e_s[k0 + k] * ldel<BF>(W1, (k0 + k) * 128 + c);
    part1[half][c] = acc;
  }
  __syncthreads();
  if (tid < 128) h1_s[tid] = fmaxf(part1[0][tid] + part1[1][tid], 0.f);
  __syncthreads();

  // layer 2: out col t = tid&63, j-quarter = tid>>6 (32 iters each)
  {
    const int t = tid & 63, qr = tid >> 6;
    const int j0 = qr * 32;
    float acc = qr ? 0.f : ldel<BF>(b2, t);
#pragma unroll
    for (int j = 0; j < 32; ++j)
      acc += h1_s[j0 + j] * ldel<BF>(W2, (j0 + j) * 64 + t);
    part2[qr][t] = acc;
  }
  __syncthreads();

  // LayerNorm on wave 0 (verified wsum path)
  if (tid < 64) {
    const float x =
        e_s[tid] + part2[0][tid] + part2[1][tid] + part2[2][tid] + part2[3][tid];
    const float mu = wsum(x) * (1.f / 64.f);
    const float d = x - mu;
    const float var = wsum(d * d) * (1.f / 64.f);
    const float h =
        d / sqrtf(var + 1e-5f) * ldel<BF>(gamma, tid) + ldel<BF>(beta, tid);
    h_s[tid] = h;
    h_table[v * 64 + tid] = h;
    const float n2 = wsum(h * h);
    if (tid == 0) norm_table[v] = sqrtf(n2);
  }
  __syncthreads();

  // q row (h@Wq+bq) and out row (h@Wo+bo; bo folded since sum(attn)=1).
  // thread: col c = tid&63, which = (tid>>6)&1 (0=q,1=o), i-half = tid>>7.
  {
    const int c = tid & 63, which = (tid >> 6) & 1, half = tid >> 7;
    const int i0 = half * 32;
    const void* W = which ? Wo : Wq;
    float acc = half ? 0.f : (which ? ldel<BF>(bo, c) : ldel<BF>(bq, c));
#pragma unroll
    for (int i = 0; i < 32; ++i)
      acc += h_s[i0 + i] * ldel<BF>(W, (i0 + i) * 64 + c);
    partq[half][which][c] = acc;
  }
  __syncthreads();
  if (tid < 128) {
    const int c = tid & 63, which = tid >> 6;
    const float r = partq[0][which][c] + partq[1][which][c];
    if (which) out_table[v * 64 + c] = r;
    else       q_table[v * 64 + c] = r;
  }
}

__global__ __launch_bounds__(256) void k_tables(
    const void* __restrict__ embed, const void* __restrict__ W1,
    const void* __restrict__ b1, const void* __restrict__ W2,
    const void* __restrict__ b2, const void* __restrict__ gamma,
    const void* __restrict__ beta, const void* __restrict__ Wq,
    const void* __restrict__ bq, const void* __restrict__ Wo,
    const void* __restrict__ bo, float* __restrict__ h_table,
    float* __restrict__ norm_table, float* __restrict__ q_table,
    float* __restrict__ out_table) {
  if (probe_bf16(embed))
    k1_body<true>(embed, W1, b1, W2, b2, gamma, beta, Wq, bq, Wo, bo, h_table,
                  norm_table, q_table, out_table);
  else
    k1_body<false>(embed, W1, b1, W2, b2, gamma, beta, Wq, bq, Wo, bo, h_table,
                   norm_table, q_table, out_table);
}

// ---- K2 (byte-identical logic to round 9, 13.9us verified) ----
__global__ __launch_bounds__(256) void k_attn(
    const int* __restrict__ seq, const float* __restrict__ h_table,
    const float* __restrict__ q_table, const float* __restrict__ out_table,
    const float* __restrict__ norm_table, const void* __restrict__ embed,
    void* __restrict__ out) {
  const bool bf = probe_bf16(embed);  // wave-uniform; store dtype only
  const int tid = threadIdx.x;
  const int wave = tid >> 6, lane = tid & 63;
  const int b = blockIdx.x * 4 + wave;
  const int* srow = seq + b * LSEQ;
  const int4 s0 = *(const int4*)(srow + 8 * lane);
  const int4 s1 = *(const int4*)(srow + 8 * lane + 4);

  // rank of token `lane` (ties share rank -> stable-by-position tie-break)
  const float nv = norm_table[lane];
  int rk = 0;
#pragma unroll
  for (int u = 0; u < 64; ++u) {
    const float nu = readlane_f(nv, u);
    rk += (nu > nv) ? 1 : 0;
  }

  const int vals[8] = {s0.x, s0.y, s0.z, s0.w, s1.x, s1.y, s1.z, s1.w};
  int keys[8];
#pragma unroll
  for (int i = 0; i < 8; ++i) {
    const int p = 8 * lane + i;
    const int r = __shfl(rk, vals[i], 64);  // dynamic gather: ds_bpermute
    keys[i] = (p < BODY) ? ((r << 15) | (p << 6) | vals[i]) : INF_KEY;
  }
  const int v_last = __builtin_amdgcn_readlane(vals[7], 63);  // srow[511]

  int winner[KSLOTS];
#pragma unroll
  for (int s = 0; s < KSLOTS; ++s) {
    int lmin = keys[0];
#pragma unroll
    for (int i = 1; i < 8; ++i) lmin = min(lmin, keys[i]);
    const int gmin = dpp_wave_min_i32(lmin);
    winner[s] = gmin;
    if (lmin == gmin) {  // keys unique (pos field) -> exactly one match
#pragma unroll
      for (int i = 0; i < 8; ++i)
        if (keys[i] == gmin) keys[i] = INF_KEY;
    }
  }

  const float qv = q_table[v_last * 64 + lane];
  float sc[KSLOTS];
#pragma unroll
  for (int s = 0; s < KSLOTS; ++s)
    sc[s] = dpp_wave_sum_f32(qv * h_table[(winner[s] & 63) * 64 + lane]) *
            0.125f;  // /sqrt(64)
  float m = sc[0];
#pragma unroll
  for (int s = 1; s < KSLOTS; ++s) m = fmaxf(m, sc[s]);
  float ex[KSLOTS], sum = 0.f;
#pragma unroll
  for (int s = 0; s < KSLOTS; ++s) {
    ex[s] = expf(sc[s] - m);
    sum += ex[s];
  }
  const float inv = 1.f / sum;
  float acc = 0.f;  // bo already folded into out_table by K1
#pragma unroll
  for (int s = 0; s < KSLOTS; ++s)
    acc += (ex[s] * inv) * out_table[(winner[s] & 63) * 64 + lane];

  if (bf) ((__hip_bfloat16*)out)[b * 64 + lane] = __float2bfloat16(acc);
  else    ((float*)out)[b * 64 + lane] = acc;
}

extern "C" void kernel_launch(void* const* d_in, const int* in_sizes, int n_in,
                              void* d_out, int out_size, void* d_ws, size_t ws_size,
                              hipStream_t stream) {
  const int* seq    = (const int*)d_in[0];
  const void* embed = d_in[1];
  const void* W1    = d_in[2];
  const void* b1    = d_in[3];
  const void* W2    = d_in[4];
  const void* b2    = d_in[5];
  const void* gamma = d_in[6];
  const void* beta  = d_in[7];
  const void* Wq    = d_in[8];
  const void* bq    = d_in[9];
  const void* Wo    = d_in[10];
  const void* bo    = d_in[11];

  float* ws         = (float*)d_ws;
  float* h_table    = ws;          // 4096 f32
  float* norm_table = ws + 4096;   // 64 f32
  float* q_table    = ws + 4224;   // 4096 f32
  float* out_table  = ws + 8320;   // 4096 f32

  k_tables<<<64, 256, 0, stream>>>(embed, W1, b1, W2, b2, gamma, beta, Wq, bq,
                                   Wo, bo, h_table, norm_table, q_table,
                                   out_table);
  k_attn<<<512, 256, 0, stream>>>(seq, h_table, q_table, out_table, norm_table,
                                  embed, d_out);
}

// Round 11
// 13.996 us; speedup vs baseline: 1.0814x; 1.0814x over previous
//
#include <hip/hip_runtime.h>
#include <hip/hip_bf16.h>

// SlotModel: B=2048, L=512, H=64, VOCAB=64, k=6 slots.
// h[b,l] depends only on token id -> 64-entry tables + per-batch top-6 scan.
// Measured structure decisions (rounds 3..10):
//  - 2 plain dispatches, non-redundant producer = best (13.9us).
//  - All single-dispatch variants worse: atomic-spin handoff 155us (XCD
//    visibility stall), grid.sync 55us, per-block redundant producer 25-44us
//    (LDS-broadcast/VALU redundancy tax).
//  - k-split 256-thr producer (round 10) regressed to 15.1us: added barriers
//    and LDS round-trips on a latency-bound (not issue-bound) kernel.
// This is the verified round-9 kernel: 64x64 producer + DPP-reduction consumer.

#define LSEQ 512
#define BODY 509       // L-3 positions eligible for slots
#define KSLOTS 6
#define INF_KEY 0x7FFFFFFF

// ---- swizzle reduction (used only in K1, 64 small blocks) ----
__device__ __forceinline__ float wsum(float x) {
#pragma unroll
  for (int off = 32; off >= 1; off >>= 1) x += __shfl_xor(x, off, 64);
  return x;
}

// ---- DPP full-wave reductions (rocPRIM wave64 pattern) ----
// row_shr:1,2,4,8 builds per-row-16 prefix; row_bcast:15 then row_bcast:31
// chains rows; lane 63 holds the full-wave result; readlane broadcasts.
__device__ __forceinline__ int dpp_wave_min_i32(int x) {
  int t;
  t = __builtin_amdgcn_update_dpp(INF_KEY, x, 0x111, 0xf, 0xf, false); x = min(x, t);
  t = __builtin_amdgcn_update_dpp(INF_KEY, x, 0x112, 0xf, 0xf, false); x = min(x, t);
  t = __builtin_amdgcn_update_dpp(INF_KEY, x, 0x114, 0xf, 0xf, false); x = min(x, t);
  t = __builtin_amdgcn_update_dpp(INF_KEY, x, 0x118, 0xf, 0xf, false); x = min(x, t);
  t = __builtin_amdgcn_update_dpp(INF_KEY, x, 0x142, 0xf, 0xf, false); x = min(x, t);
  t = __builtin_amdgcn_update_dpp(INF_KEY, x, 0x143, 0xf, 0xf, false); x = min(x, t);
  return __builtin_amdgcn_readlane(x, 63);
}
__device__ __forceinline__ float dpp_wave_sum_f32(float x) {
  int t;
  t = __builtin_amdgcn_update_dpp(0, __float_as_int(x), 0x111, 0xf, 0xf, false); x += __int_as_float(t);
  t = __builtin_amdgcn_update_dpp(0, __float_as_int(x), 0x112, 0xf, 0xf, false); x += __int_as_float(t);
  t = __builtin_amdgcn_update_dpp(0, __float_as_int(x), 0x114, 0xf, 0xf, false); x += __int_as_float(t);
  t = __builtin_amdgcn_update_dpp(0, __float_as_int(x), 0x118, 0xf, 0xf, false); x += __int_as_float(t);
  t = __builtin_amdgcn_update_dpp(0, __float_as_int(x), 0x142, 0xf, 0xf, false); x += __int_as_float(t);
  t = __builtin_amdgcn_update_dpp(0, __float_as_int(x), 0x143, 0xf, 0xf, false); x += __int_as_float(t);
  return __int_as_float(__builtin_amdgcn_readlane(__float_as_int(x), 63));
}
__device__ __forceinline__ float readlane_f(float x, int u) {
  return __int_as_float(__builtin_amdgcn_readlane(__float_as_int(x), u));
}

// Dtype probe (verified rounds 2-10): first 256 ushorts of embed. True bf16
// embed ~N(0,0.02^2) -> exponent < 127; if f32, low-mantissa halves have
// ~random exponents -> detection certain. Wave-uniform.
__device__ __forceinline__ bool probe_bf16(const void* embed) {
  const ushort* e = (const ushort*)embed;
  const int lane = threadIdx.x & 63;
  bool bad = false;
#pragma unroll
  for (int i = 0; i < 4; ++i) {
    const int exp = (e[lane * 4 + i] >> 7) & 0xFF;
    if (exp >= 127) bad = true;
  }
  return !__any(bad);
}

template <bool BF>
__device__ __forceinline__ float ldel(const void* p, int i) {
  if (BF) return __bfloat162float(((const __hip_bfloat16*)p)[i]);
  return ((const float*)p)[i];
}
template <bool BF>
__device__ __forceinline__ float2 ldpair(const void* p, int i) {
  if (BF) {
    const uint u = *(const uint*)((const ushort*)p + i);
    return make_float2(__uint_as_float(u << 16),
                       __uint_as_float(u & 0xFFFF0000u));
  }
  return *(const float2*)((const float*)p + i);
}

// ---- K1 (verified rounds 3/9): 64 blocks x 64 threads, one token each.
// Produces h row, q row (=h@Wq+bq), out row (=h@Wo+bo folded), norm. ----
template <bool BF>
__device__ __forceinline__ void k1_body(
    const void* embed, const void* W1, const void* b1, const void* W2,
    const void* b2, const void* gamma, const void* beta, const void* Wq,
    const void* bq, const void* Wo, const void* bo, float* h_table,
    float* norm_table, float* q_table, float* out_table) {
  const int v = blockIdx.x, t = threadIdx.x;
  __shared__ float e_s[64];
  __shared__ float h1_s[128];
  __shared__ float h_s[64];
  e_s[t] = ldel<BF>(embed, v * 64 + t);
  __syncthreads();
  float a0 = ldel<BF>(b1, 2 * t);
  float a1 = ldel<BF>(b1, 2 * t + 1);
#pragma unroll
  for (int k = 0; k < 64; ++k) {
    const float ek = e_s[k];
    const float2 w = ldpair<BF>(W1, k * 128 + 2 * t);
    a0 += ek * w.x;
    a1 += ek * w.y;
  }
  h1_s[2 * t] = fmaxf(a0, 0.f);
  h1_s[2 * t + 1] = fmaxf(a1, 0.f);
  __syncthreads();
  float f = ldel<BF>(b2, t);
#pragma unroll
  for (int j = 0; j < 128; ++j) f += h1_s[j] * ldel<BF>(W2, j * 64 + t);
  const float x = e_s[t] + f;
  const float mu = wsum(x) * (1.f / 64.f);
  const float d = x - mu;
  const float var = wsum(d * d) * (1.f / 64.f);
  const float h = d / sqrtf(var + 1e-5f) * ldel<BF>(gamma, t) + ldel<BF>(beta, t);
  h_table[v * 64 + t] = h;
  h_s[t] = h;
  const float n2 = wsum(h * h);
  if (t == 0) norm_table[v] = sqrtf(n2);
  __syncthreads();
  float q = ldel<BF>(bq, t);
  float o = ldel<BF>(bo, t);   // bo folded: sum(attn)==1
#pragma unroll
  for (int i = 0; i < 64; ++i) {
    const float hi = h_s[i];
    q += hi * ldel<BF>(Wq, i * 64 + t);
    o += hi * ldel<BF>(Wo, i * 64 + t);
  }
  q_table[v * 64 + t] = q;
  out_table[v * 64 + t] = o;
}

__global__ __launch_bounds__(64) void k_tables(
    const void* __restrict__ embed, const void* __restrict__ W1,
    const void* __restrict__ b1, const void* __restrict__ W2,
    const void* __restrict__ b2, const void* __restrict__ gamma,
    const void* __restrict__ beta, const void* __restrict__ Wq,
    const void* __restrict__ bq, const void* __restrict__ Wo,
    const void* __restrict__ bo, float* __restrict__ h_table,
    float* __restrict__ norm_table, float* __restrict__ q_table,
    float* __restrict__ out_table) {
  if (probe_bf16(embed))
    k1_body<true>(embed, W1, b1, W2, b2, gamma, beta, Wq, bq, Wo, bo, h_table,
                  norm_table, q_table, out_table);
  else
    k1_body<false>(embed, W1, b1, W2, b2, gamma, beta, Wq, bq, Wo, bo, h_table,
                   norm_table, q_table, out_table);
}

// ---- K2: 512 blocks x 256, one batch row per wave. Rank-key top-6
// (== jax.lax.top_k desc-stable), DPP reductions, softmax, weighted sum. ----
__global__ __launch_bounds__(256) void k_attn(
    const int* __restrict__ seq, const float* __restrict__ h_table,
    const float* __restrict__ q_table, const float* __restrict__ out_table,
    const float* __restrict__ norm_table, const void* __restrict__ embed,
    void* __restrict__ out) {
  const bool bf = probe_bf16(embed);  // wave-uniform; store dtype only
  const int tid = threadIdx.x;
  const int wave = tid >> 6, lane = tid & 63;
  const int b = blockIdx.x * 4 + wave;
  const int* srow = seq + b * LSEQ;
  const int4 s0 = *(const int4*)(srow + 8 * lane);
  const int4 s1 = *(const int4*)(srow + 8 * lane + 4);

  // rank of token `lane`: count of strictly-greater norms (ties share rank
  // -> stable-by-position tie-break). readlane: constant index, VALU-only.
  const float nv = norm_table[lane];
  int rk = 0;
#pragma unroll
  for (int u = 0; u < 64; ++u) {
    const float nu = readlane_f(nv, u);
    rk += (nu > nv) ? 1 : 0;
  }

  const int vals[8] = {s0.x, s0.y, s0.z, s0.w, s1.x, s1.y, s1.z, s1.w};
  int keys[8];
#pragma unroll
  for (int i = 0; i < 8; ++i) {
    const int p = 8 * lane + i;
    const int r = __shfl(rk, vals[i], 64);  // dynamic gather: ds_bpermute
    keys[i] = (p < BODY) ? ((r << 15) | (p << 6) | vals[i]) : INF_KEY;
  }
  const int v_last = __builtin_amdgcn_readlane(vals[7], 63);  // srow[511]

  int winner[KSLOTS];
#pragma unroll
  for (int s = 0; s < KSLOTS; ++s) {
    int lmin = keys[0];
#pragma unroll
    for (int i = 1; i < 8; ++i) lmin = min(lmin, keys[i]);
    const int gmin = dpp_wave_min_i32(lmin);
    winner[s] = gmin;
    if (lmin == gmin) {  // keys unique (pos field) -> exactly one match
#pragma unroll
      for (int i = 0; i < 8; ++i)
        if (keys[i] == gmin) keys[i] = INF_KEY;
    }
  }

  const float qv = q_table[v_last * 64 + lane];
  float sc[KSLOTS];
#pragma unroll
  for (int s = 0; s < KSLOTS; ++s)
    sc[s] = dpp_wave_sum_f32(qv * h_table[(winner[s] & 63) * 64 + lane]) *
            0.125f;  // /sqrt(64)
  float m = sc[0];
#pragma unroll
  for (int s = 1; s < KSLOTS; ++s) m = fmaxf(m, sc[s]);
  float ex[KSLOTS], sum = 0.f;
#pragma unroll
  for (int s = 0; s < KSLOTS; ++s) {
    ex[s] = expf(sc[s] - m);
    sum += ex[s];
  }
  const float inv = 1.f / sum;
  float acc = 0.f;  // bo already folded into out_table by K1
#pragma unroll
  for (int s = 0; s < KSLOTS; ++s)
    acc += (ex[s] * inv) * out_table[(winner[s] & 63) * 64 + lane];

  if (bf) ((__hip_bfloat16*)out)[b * 64 + lane] = __float2bfloat16(acc);
  else    ((float*)out)[b * 64 + lane] = acc;
}

extern "C" void kernel_launch(void* const* d_in, const int* in_sizes, int n_in,
                              void* d_out, int out_size, void* d_ws, size_t ws_size,
                              hipStream_t stream) {
  const int* seq    = (const int*)d_in[0];
  const void* embed = d_in[1];
  const void* W1    = d_in[2];
  const void* b1    = d_in[3];
  const void* W2    = d_in[4];
  const void* b2    = d_in[5];
  const void* gamma = d_in[6];
  const void* beta  = d_in[7];
  const void* Wq    = d_in[8];
  const void* bq    = d_in[9];
  const void* Wo    = d_in[10];
  const void* bo    = d_in[11];

  float* ws         = (float*)d_ws;
  float* h_table    = ws;          // 4096 f32
  float* norm_table = ws + 4096;   // 64 f32
  float* q_table    = ws + 4224;   // 4096 f32
  float* out_table  = ws + 8320;   // 4096 f32

  k_tables<<<64, 64, 0, stream>>>(embed, W1, b1, W2, b2, gamma, beta, Wq, bq,
                                  Wo, bo, h_table, norm_table, q_table,
                                  out_table);
  k_attn<<<512, 256, 0, stream>>>(seq, h_table, q_table, out_table, norm_table,
                                  embed, d_out);
}